// Round 2
// baseline (838.422 us; speedup 1.0000x reference)
//
#include <hip/hip_runtime.h>
#include <stdint.h>

#define NBLK 2048
#define NTHR 256

// ws layout (uint32 words)
#define HA_OFF   0        // 4096  histA (top 12 bits)
#define HB_OFF   4096     // 3*4096 histB (mid 12 bits)
#define HC_OFF   16384    // 3*256  histC (low 8 bits)
#define SELP_OFF 17152    // 3 prefixes
#define SELR_OFF 17155    // 3 residual ranks
#define WS_WORDS 17158

__global__ void init_sel(uint32_t* ws, uint32_t r0, uint32_t r1, uint32_t r2) {
  ws[SELR_OFF + 0] = r0; ws[SELR_OFF + 1] = r1; ws[SELR_OFF + 2] = r2;
  ws[SELP_OFF + 0] = 0;  ws[SELP_OFF + 1] = 0;  ws[SELP_OFF + 2] = 0;
}

__device__ __forceinline__ uint32_t akey(float v) {
  return __float_as_uint(v) & 0x7FFFFFFFu;   // |v| bits; monotone for non-negative floats
}

__global__ void hist_top12(const float* __restrict__ g, long long n,
                           uint32_t* __restrict__ hist) {
  __shared__ uint32_t h[4096];
  for (int i = threadIdx.x; i < 4096; i += NTHR) h[i] = 0;
  __syncthreads();
  long long tid = (long long)blockIdx.x * NTHR + threadIdx.x;
  long long stride = (long long)gridDim.x * NTHR;
  long long n4 = n >> 2;
  const float4* g4 = (const float4*)g;
  for (long long i = tid; i < n4; i += stride) {
    float4 v = g4[i];
    atomicAdd(&h[akey(v.x) >> 20], 1u);
    atomicAdd(&h[akey(v.y) >> 20], 1u);
    atomicAdd(&h[akey(v.z) >> 20], 1u);
    atomicAdd(&h[akey(v.w) >> 20], 1u);
  }
  for (long long i = (n4 << 2) + tid; i < n; i += stride)
    atomicAdd(&h[akey(g[i]) >> 20], 1u);
  __syncthreads();
  for (int i = threadIdx.x; i < 4096; i += NTHR)
    if (h[i]) atomicAdd(&hist[i], h[i]);
}

__global__ void hist_mid12(const float* __restrict__ g, long long n,
                           const uint32_t* __restrict__ ws,
                           uint32_t* __restrict__ histB) {
  __shared__ uint32_t h[3 * 4096];   // 48 KiB
  for (int i = threadIdx.x; i < 3 * 4096; i += NTHR) h[i] = 0;
  __syncthreads();
  uint32_t p0 = ws[SELP_OFF + 0], p1 = ws[SELP_OFF + 1], p2 = ws[SELP_OFF + 2];
  long long tid = (long long)blockIdx.x * NTHR + threadIdx.x;
  long long stride = (long long)gridDim.x * NTHR;
  long long n4 = n >> 2;
  const float4* g4 = (const float4*)g;
  for (long long i = tid; i < n4; i += stride) {
    float4 v = g4[i];
    float vv[4] = {v.x, v.y, v.z, v.w};
    #pragma unroll
    for (int l = 0; l < 4; ++l) {
      uint32_t key = akey(vv[l]);
      uint32_t top = key >> 20, mid = (key >> 8) & 4095u;
      if (top == p0) atomicAdd(&h[mid], 1u);
      if (top == p1) atomicAdd(&h[4096 + mid], 1u);
      if (top == p2) atomicAdd(&h[8192 + mid], 1u);
    }
  }
  for (long long i = (n4 << 2) + tid; i < n; i += stride) {
    uint32_t key = akey(g[i]);
    uint32_t top = key >> 20, mid = (key >> 8) & 4095u;
    if (top == p0) atomicAdd(&h[mid], 1u);
    if (top == p1) atomicAdd(&h[4096 + mid], 1u);
    if (top == p2) atomicAdd(&h[8192 + mid], 1u);
  }
  __syncthreads();
  for (int i = threadIdx.x; i < 3 * 4096; i += NTHR)
    if (h[i]) atomicAdd(&histB[i], h[i]);
}

__global__ void hist_low8(const float* __restrict__ g, long long n,
                          const uint32_t* __restrict__ ws,
                          uint32_t* __restrict__ histC) {
  __shared__ uint32_t h[3 * 256];
  for (int i = threadIdx.x; i < 3 * 256; i += NTHR) h[i] = 0;
  __syncthreads();
  uint32_t p0 = ws[SELP_OFF + 0], p1 = ws[SELP_OFF + 1], p2 = ws[SELP_OFF + 2];
  long long tid = (long long)blockIdx.x * NTHR + threadIdx.x;
  long long stride = (long long)gridDim.x * NTHR;
  long long n4 = n >> 2;
  const float4* g4 = (const float4*)g;
  for (long long i = tid; i < n4; i += stride) {
    float4 v = g4[i];
    float vv[4] = {v.x, v.y, v.z, v.w};
    #pragma unroll
    for (int l = 0; l < 4; ++l) {
      uint32_t key = akey(vv[l]);
      uint32_t top = key >> 8, lo = key & 255u;
      if (top == p0) atomicAdd(&h[lo], 1u);
      if (top == p1) atomicAdd(&h[256 + lo], 1u);
      if (top == p2) atomicAdd(&h[512 + lo], 1u);
    }
  }
  for (long long i = (n4 << 2) + tid; i < n; i += stride) {
    uint32_t key = akey(g[i]);
    uint32_t top = key >> 8, lo = key & 255u;
    if (top == p0) atomicAdd(&h[lo], 1u);
    if (top == p1) atomicAdd(&h[256 + lo], 1u);
    if (top == p2) atomicAdd(&h[512 + lo], 1u);
  }
  __syncthreads();
  for (int i = threadIdx.x; i < 3 * 256; i += NTHR)
    if (h[i]) atomicAdd(&histC[i], h[i]);
}

// One block per rank k. Finds bin b with cum[b] <= r < cum[b]+h[b];
// appends b to prefix, rebases rank.
__global__ void scan_select(const uint32_t* __restrict__ hist, int nbins,
                            int khStride, int bits, uint32_t* __restrict__ ws) {
  int k = blockIdx.x;
  const uint32_t* h = hist + (size_t)k * khStride;
  __shared__ uint32_t hs[4096];
  __shared__ uint32_t ps[NTHR + 1];
  int t = threadIdx.x;
  for (int i = t; i < nbins; i += NTHR) hs[i] = h[i];
  __syncthreads();
  int chunk = nbins / NTHR;
  uint32_t s = 0;
  for (int j = 0; j < chunk; ++j) s += hs[t * chunk + j];
  ps[t] = s;
  __syncthreads();
  if (t == 0) {
    uint32_t run = 0;
    for (int i = 0; i < NTHR; ++i) { uint32_t v = ps[i]; ps[i] = run; run += v; }
    ps[NTHR] = run;
  }
  __syncthreads();
  uint32_t r = ws[SELR_OFF + k];
  uint32_t E = ps[t];
  for (int j = 0; j < chunk; ++j) {
    int b = t * chunk + j;
    uint32_t c = hs[b];
    if (r >= E && (r - E) < c) {   // exactly one winner thread
      ws[SELP_OFF + k] = (ws[SELP_OFF + k] << bits) | (uint32_t)b;
      ws[SELR_OFF + k] = r - E;
    }
    E += c;
  }
}

// Region params (EXP_BITS 2,3,5,6; mb = 7-eb):
// r0: mb=5 min_e=0   max_e=2  max_val=7.875
// r1: mb=4 min_e=-2  max_e=4  max_val=31
// r2: mb=2 min_e=-14 max_e=16 max_val=114688
// r3: mb=1 min_e=-30 max_e=32 max_val=6442450944
__device__ __forceinline__ float qone(float xi, float gi,
                                      float T0, float T1, float T2) {
  float ga = fabsf(gi);
  int r = (int)(ga > T0) + (int)(ga > T1) + (int)(ga > T2);
  float maxv = r == 0 ? 7.875f : r == 1 ? 31.0f : r == 2 ? 114688.0f : 6442450944.0f;
  int   mb   = r == 0 ? 5 : r == 1 ? 4 : r == 2 ? 2 : 1;
  int   mine = r == 0 ? 0 : r == 1 ? -2 : r == 2 ? -14 : -30;
  int   maxe = r == 0 ? 2 : r == 1 ? 4 : r == 2 ? 16 : 32;
  float minv = __uint_as_float((uint32_t)(mine - mb + 127) << 23);  // 2^(min_e-mb)
  float ax = fminf(fabsf(xi), maxv);        // clip
  bool  z  = ax < minv;                     // zero mask
  float xa = fmaxf(ax, minv);
  int e = (int)((__float_as_uint(xa) >> 23) & 255u) - 127;  // exact floor(log2)
  e = min(max(e, mine), maxe);
  float p    = __uint_as_float((uint32_t)(e + 127) << 23);   // 2^e
  float invp = __uint_as_float((uint32_t)(127 - e) << 23);   // 2^-e
  float mf   = fmaf(xa, invp, -1.0f);       // exact in the Sterbenz range
  float lev  = __uint_as_float((uint32_t)(127 + mb) << 23);  // 2^mb
  float ilev = __uint_as_float((uint32_t)(127 - mb) << 23);  // 2^-mb
  float mq = rintf(mf * lev) * ilev;        // round-half-even == np.round
  mq = fminf(fmaxf(mq, 0.0f), 1.0f - ilev);
  float res = p * (1.0f + mq);
  res = (xi < 0.0f) ? -res : res;
  return z ? 0.0f : res;
}

__global__ void quant_kernel(const float* __restrict__ x, const float* __restrict__ g,
                             float* __restrict__ out, long long n,
                             const uint32_t* __restrict__ ws) {
  float T0 = __uint_as_float(ws[SELP_OFF + 0]);
  float T1 = __uint_as_float(ws[SELP_OFF + 1]);
  float T2 = __uint_as_float(ws[SELP_OFF + 2]);
  long long tid = (long long)blockIdx.x * NTHR + threadIdx.x;
  long long stride = (long long)gridDim.x * NTHR;
  long long n4 = n >> 2;
  const float4* x4 = (const float4*)x;
  const float4* g4 = (const float4*)g;
  float4* o4 = (float4*)out;
  for (long long i = tid; i < n4; i += stride) {
    float4 xv = x4[i];
    float4 gv = g4[i];
    float4 ov;
    ov.x = qone(xv.x, gv.x, T0, T1, T2);
    ov.y = qone(xv.y, gv.y, T0, T1, T2);
    ov.z = qone(xv.z, gv.z, T0, T1, T2);
    ov.w = qone(xv.w, gv.w, T0, T1, T2);
    o4[i] = ov;
  }
  for (long long i = (n4 << 2) + tid; i < n; i += stride)
    out[i] = qone(x[i], g[i], T0, T1, T2);
}

extern "C" void kernel_launch(void* const* d_in, const int* in_sizes, int n_in,
                              void* d_out, int out_size, void* d_ws, size_t ws_size,
                              hipStream_t stream) {
  const float* x = (const float*)d_in[0];
  const float* g = (const float*)d_in[1];
  float* out = (float*)d_out;
  long long n = (long long)in_sizes[0];
  uint32_t* ws = (uint32_t*)d_ws;

  hipMemsetAsync(d_ws, 0, WS_WORDS * sizeof(uint32_t), stream);

  // np.quantile semantics: virtual index (n-1)*q; for data elements,
  // (ga > q) <=> (ga > sorted[floor((n-1)*q)]) — exact, needs only rank r.
  uint32_t r[3];
  for (int i = 0; i < 3; ++i) {
    double v = (double)(n - 1) * (0.25 * (i + 1));
    r[i] = (uint32_t)v;   // floor for positive
  }

  init_sel<<<1, 1, 0, stream>>>(ws, r[0], r[1], r[2]);
  hist_top12<<<NBLK, NTHR, 0, stream>>>(g, n, ws + HA_OFF);
  scan_select<<<3, NTHR, 0, stream>>>(ws + HA_OFF, 4096, 0, 12, ws);
  hist_mid12<<<NBLK, NTHR, 0, stream>>>(g, n, ws, ws + HB_OFF);
  scan_select<<<3, NTHR, 0, stream>>>(ws + HB_OFF, 4096, 4096, 12, ws);
  hist_low8<<<NBLK, NTHR, 0, stream>>>(g, n, ws, ws + HC_OFF);
  scan_select<<<3, NTHR, 0, stream>>>(ws + HC_OFF, 256, 256, 8, ws);
  quant_kernel<<<NBLK, NTHR, 0, stream>>>(x, g, out, n, ws);
}